// Round 11
// baseline (145.984 us; speedup 1.0000x reference)
//
#include <hip/hip_runtime.h>
#include <hip/hip_bf16.h>

// Problem: x(4,256,64,64), offset(4,18,64,64), mask(4,9,64,64),
// weight(256,256,3,3) -> out(4,256,64,64). stride=1, pad=1, K=3.
// R11: software-pipelined fused sample+GEMM.
//  - offs/mask loads two kk ahead (f32x4, wave-uniform)
//  - corner gathers (coalesced 512B rows, R10 win) one kk ahead, staged in
//    regs; MFMA(kk) runs between issue and combine -> latency hidden
//  - combine uses packed f32x2 (v_pk_fma_f32) + v_cvt_pk_bf16_f32
//  - A-tile LDS: oct-stride 33 padded chunks (bank-balanced), double-buffered
#define BN 4
#define CN 256
#define HN 64
#define WN 64
#define ON 256
#define KKN 9
#define HWN 4096
#define KDIM 2304
#define KC 288

using frag_ab = __attribute__((ext_vector_type(8))) short;
using frag_cd = __attribute__((ext_vector_type(4))) float;
using short4v = __attribute__((ext_vector_type(4))) short;
using f32x2   = __attribute__((ext_vector_type(2))) float;
using f32x4   = __attribute__((ext_vector_type(4))) float;

static __device__ inline short f2bf(float f) {
    union { float f; unsigned u; } v; v.f = f;
    unsigned r = v.u + 0x7fffu + ((v.u >> 16) & 1u);
    return (short)(r >> 16);
}
static __device__ inline f32x2 unpk(unsigned u) {
    union { unsigned v; float f; } a, b;
    a.v = u << 16;
    b.v = u & 0xffff0000u;
    f32x2 r; r[0] = a.f; r[1] = b.f; return r;
}

// ---------- kernel 1: prep = transpose x -> BHWC bf16 | repack weight ------
__global__ __launch_bounds__(256) void prep_kernel(const float* __restrict__ x,
                                                   const float* __restrict__ wsrc,
                                                   short* __restrict__ xb16,
                                                   short* __restrict__ wtb) {
    int bidx = blockIdx.x;
    int tid  = threadIdx.x;
    if (bidx < 1024) {
        __shared__ float tile[64][65];
        int b   = bidx >> 8;
        int rem = bidx & 255;
        int c0  = (rem >> 6) * 64;
        int p0  = (rem & 63) * 64;
        int tp = tid & 63, tc = tid >> 6;
        for (int i = 0; i < 16; ++i) {
            int c = tc + i * 4;
            tile[c][tp] = x[(b * CN + c0 + c) * HWN + p0 + tp];
        }
        __syncthreads();
        int tcc = tid & 63, tpp = tid >> 6;
        for (int i = 0; i < 16; ++i) {
            int p = tpp + i * 4;
            xb16[(b * HWN + p0 + p) * CN + c0 + tcc] = f2bf(tile[tcc][p]);
        }
    } else {
        int chunk = (bidx - 1024) * 256 + tid;
        int ob  = chunk / (KC * 64);
        int rem = chunk - ob * (KC * 64);
        int kc  = rem >> 6;
        int row = rem & 63;
        int o   = ob * 64 + row;
        int kk  = kc >> 5;
        int oct = kc & 31;
        frag_ab v;
        #pragma unroll
        for (int e = 0; e < 8; ++e)
            v[e] = f2bf(wsrc[(o * CN + oct * 8 + e) * 9 + kk]);
        *(frag_ab*)&wtb[(size_t)chunk * 8] = v;
    }
}

// ---------- kernel 2: pipelined fused sample + GEMM ----------
__global__ __launch_bounds__(256, 2) void fused_kernel(const short* __restrict__ xb16,
                                                       const short* __restrict__ wtb,
                                                       const float* __restrict__ offs,
                                                       const float* __restrict__ maskp,
                                                       float* __restrict__ out) {
    __shared__ union {
        short Ab[2][8448];        // 2 x 16.5 KB (1056 padded chunks, stride 33)
        float outb[32 * 257];
    } sm;
    int tid = threadIdx.x;
    int m0  = blockIdx.x * 32;
    int b   = m0 >> 12;
    int h   = (m0 >> 6) & 63;
    int w0  = m0 & 63;
    int wv  = tid >> 6, lane = tid & 63;
    int q   = lane >> 4, r = lane & 15;
    int wrow0 = w0 + wv * 8;                    // this wave's 8 m-rows
    int wbase = 33 * (lane >> 1) * 8 + (lane & 1) * 4;

    frag_cd acc[2][4];
    #pragma unroll
    for (int i = 0; i < 2; ++i)
        #pragma unroll
        for (int j = 0; j < 4; ++j)
            acc[i][j] = (frag_cd){0.f, 0.f, 0.f, 0.f};

    f32x4   dyS[2][2], dxS[2][2], mvS[2][2];   // two-deep offs pipeline
    short4v pv[8][4];                           // staged corner rows
    float   cwv[8][4];                          // corner weights

#define LOAD_OFFS(kk, st)                                                   \
    {                                                                       \
        int ob_ = ((b * 18 + (kk) * 2) * 64 + h) * 64 + wrow0;              \
        dyS[st][0] = *(const f32x4*)&offs[ob_];                             \
        dyS[st][1] = *(const f32x4*)&offs[ob_ + 4];                         \
        dxS[st][0] = *(const f32x4*)&offs[ob_ + HWN];                       \
        dxS[st][1] = *(const f32x4*)&offs[ob_ + HWN + 4];                   \
        int mb_ = ((b * 9 + (kk)) * 64 + h) * 64 + wrow0;                   \
        mvS[st][0] = *(const f32x4*)&maskp[mb_];                            \
        mvS[st][1] = *(const f32x4*)&maskp[mb_ + 4];                        \
    }

#define GATHERS(kk, st)                                                     \
    {                                                                       \
        const int ki_ = (kk) / 3, kj_ = (kk) % 3;                           \
        _Pragma("unroll")                                                   \
        for (int i = 0; i < 8; ++i) {                                       \
            float dyi = dyS[st][i >> 2][i & 3];                             \
            float dxi = dxS[st][i >> 2][i & 3];                             \
            float mvi = mvS[st][i >> 2][i & 3];                             \
            int wc = wrow0 + i;                                             \
            float py = (float)(h - 1 + ki_) + dyi;                          \
            float px = (float)(wc - 1 + kj_) + dxi;                         \
            float y0f = floorf(py), x0f = floorf(px);                       \
            float wy = py - y0f, wx = px - x0f;                             \
            int y0 = (int)y0f, x0 = (int)x0f;                               \
            _Pragma("unroll")                                               \
            for (int cy = 0; cy < 2; ++cy) {                                \
                _Pragma("unroll")                                           \
                for (int cx = 0; cx < 2; ++cx) {                            \
                    int yy = y0 + cy, xx = x0 + cx;                         \
                    bool valid =                                            \
                        (yy >= 0 && yy < HN && xx >= 0 && xx < WN);         \
                    int yc = min(max(yy, 0), HN - 1);                       \
                    int xc = min(max(xx, 0), WN - 1);                       \
                    int cb_ = ((b * HN + yc) * WN + xc) * CN;               \
                    float wgt = (cy ? wy : 1.f - wy) *                      \
                                (cx ? wx : 1.f - wx) * mvi;                 \
                    cwv[i][cy * 2 + cx] = valid ? wgt : 0.f;                \
                    pv[i][cy * 2 + cx] =                                    \
                        *(const short4v*)&xb16[cb_ + lane * 4];             \
                }                                                           \
            }                                                               \
        }                                                                   \
    }

#define COMBINE(dstp)                                                       \
    {                                                                       \
        short* dst_ = (dstp);                                               \
        _Pragma("unroll")                                                   \
        for (int i = 0; i < 8; ++i) {                                       \
            union { short4v s; unsigned u[2]; } a0, a1, a2, a3;             \
            a0.s = pv[i][0]; a1.s = pv[i][1];                               \
            a2.s = pv[i][2]; a3.s = pv[i][3];                               \
            short4v res;                                                    \
            _Pragma("unroll")                                               \
            for (int p = 0; p < 2; ++p) {                                   \
                f32x2 s2 = unpk(a0.u[p]) * cwv[i][0];                       \
                s2 += unpk(a1.u[p]) * cwv[i][1];                            \
                s2 += unpk(a2.u[p]) * cwv[i][2];                            \
                s2 += unpk(a3.u[p]) * cwv[i][3];                            \
                __hip_bfloat162 p2 =                                        \
                    __float22bfloat162_rn(make_float2(s2[0], s2[1]));       \
                res[2 * p]     = *(short*)&p2.x;                            \
                res[2 * p + 1] = *(short*)&p2.y;                            \
            }                                                               \
            *(short4v*)&dst_[wbase + (wv * 8 + i) * 8] = res;               \
        }                                                                   \
    }

    // ---- preamble: kk=0 sampled fully; offs for 0,1 loaded ----
    LOAD_OFFS(0, 0)
    LOAD_OFFS(1, 1)
    GATHERS(0, 0)
    COMBINE(sm.Ab[0])
    __syncthreads();

    #pragma unroll
    for (int kk = 0; kk < KKN; ++kk) {
        short* cur = sm.Ab[kk & 1];
        if (kk + 1 < KKN) {
            GATHERS(kk + 1, (kk + 1) & 1)      // issue next kk's gathers
            if (kk + 2 < KKN) LOAD_OFFS(kk + 2, kk & 1)
        }
        // ---- MFMA phase: 8 k16-steps; A from LDS, B direct global (L2) ----
        #pragma unroll
        for (int ks = 0; ks < 8; ++ks) {
            frag_ab af[2], bf[4];
            #pragma unroll
            for (int i = 0; i < 2; ++i)
                af[i] = *(const frag_ab*)
                    &cur[(33 * (ks * 4 + q) + i * 16 + r) * 8];
            #pragma unroll
            for (int j = 0; j < 4; ++j)
                bf[j] = *(const frag_ab*)
                    &wtb[(((size_t)wv * KC + kk * 32 + ks * 4 + q) * 64
                          + j * 16 + r) * 8];
            #pragma unroll
            for (int i = 0; i < 2; ++i)
                #pragma unroll
                for (int j = 0; j < 4; ++j)
                    acc[i][j] = __builtin_amdgcn_mfma_f32_16x16x32_bf16(
                        af[i], bf[j], acc[i][j], 0, 0, 0);
        }
        if (kk + 1 < KKN) COMBINE(sm.Ab[(kk + 1) & 1])
        __syncthreads();
    }

    // ---- epilogue: acc (row=i*16+q*4+reg, col=wv*64+j*16+r) -> LDS -> BOHW
    #pragma unroll
    for (int i = 0; i < 2; ++i)
        #pragma unroll
        for (int j = 0; j < 4; ++j) {
            int ml = i * 16 + q * 4;
            int ol = wv * 64 + j * 16 + r;
            sm.outb[(ml + 0) * 257 + ol] = acc[i][j][0];
            sm.outb[(ml + 1) * 257 + ol] = acc[i][j][1];
            sm.outb[(ml + 2) * 257 + ol] = acc[i][j][2];
            sm.outb[(ml + 3) * 257 + ol] = acc[i][j][3];
        }
    __syncthreads();
    {
        int ww = tid & 31;
        int og = tid >> 5;
        #pragma unroll
        for (int oo = 0; oo < 32; ++oo) {
            int o = oo * 8 + og;
            out[(((size_t)b * ON + o) * HN + h) * WN + w0 + ww] =
                sm.outb[ww * 257 + o];
        }
    }
#undef LOAD_OFFS
#undef GATHERS
#undef COMBINE
}

extern "C" void kernel_launch(void* const* d_in, const int* in_sizes, int n_in,
                              void* d_out, int out_size, void* d_ws, size_t ws_size,
                              hipStream_t stream) {
    const float* x      = (const float*)d_in[0];
    const float* offset = (const float*)d_in[1];
    const float* mask   = (const float*)d_in[2];
    const float* weight = (const float*)d_in[3];
    float* out = (float*)d_out;

    short* xb16 = (short*)d_ws;
    short* wtb  = (short*)((char*)d_ws + 8388608);

    hipLaunchKernelGGL(prep_kernel,  dim3(1312), dim3(256), 0, stream,
                       x, weight, xb16, wtb);
    hipLaunchKernelGGL(fused_kernel, dim3(512),  dim3(256), 0, stream,
                       xb16, wtb, offset, mask, out);
}